// Round 3
// baseline (539.527 us; speedup 1.0000x reference)
//
#include <hip/hip_runtime.h>

// GroupedLinear: out[T,OUT] = x[T,IN] @ W[e]^T + bias[e], expert-ranged rows.
// E=8, IN=OUT=2048, T=16384. fp32 in/out, bf16 MFMA compute.
//
// Round 5: GEMM ported to the 256x256 8-phase template (T2+T3+T4+T5).
//   Pass 1: fp32->bf16 cvt of x and W into workspace (unchanged from R4).
//   Pass 2: 256² tile, 512 thr / 8 waves (2M x 4N), BK=64, 128 KiB LDS.
//     buf0 = even K-tiles, buf1 = odd. One half-tile (2 gload_lds/thread)
//     staged per phase, staggered one+ barrier-phases after the region's
//     last ds_read. vmcnt(6) only at phases 4 and 8. LDS read swizzle
//     byte ^= ((row&7)<<4), same involution pre-applied to global source
//     (linear LDS dest for global_load_lds). setprio(1) around MFMA.
// Fallback to the verified fused f32 kernel if ws_size < 134 MB.

typedef __attribute__((ext_vector_type(8))) short short8;
typedef __attribute__((ext_vector_type(4))) float f32x4;

__device__ __forceinline__ unsigned short f2bf(float f) {
    unsigned u = __builtin_bit_cast(unsigned, f);
    u += 0x7FFFu + ((u >> 16) & 1u);
    return (unsigned short)(u >> 16);
}

// ---------------------------------------------------------------------------
// Pass 1: fp32 -> bf16 conversion, 8 elems/thread/iter, grid-stride.
// ---------------------------------------------------------------------------
__global__ __launch_bounds__(256)
void cvt_f32_bf16(const float* __restrict__ in, unsigned short* __restrict__ out, int n8)
{
    int i = blockIdx.x * blockDim.x + threadIdx.x;
    const int stride = gridDim.x * blockDim.x;
    const f32x4* __restrict__ in4 = (const f32x4*)in;
    short8* __restrict__ out8 = (short8*)out;
    for (; i < n8; i += stride) {
        f32x4 a = in4[2 * i];
        f32x4 b = in4[2 * i + 1];
        short8 o;
        o[0] = (short)f2bf(a.x); o[1] = (short)f2bf(a.y);
        o[2] = (short)f2bf(a.z); o[3] = (short)f2bf(a.w);
        o[4] = (short)f2bf(b.x); o[5] = (short)f2bf(b.y);
        o[6] = (short)f2bf(b.z); o[7] = (short)f2bf(b.w);
        out8[i] = o;
    }
}

// ---------------------------------------------------------------------------
// Pass 2: bf16 grouped GEMM, 256² 8-phase schedule.
// ---------------------------------------------------------------------------
__device__ __forceinline__ void gload16(const unsigned short* g, unsigned short* l)
{
    __builtin_amdgcn_global_load_lds(
        (const __attribute__((address_space(1))) unsigned int*)g,
        (__attribute__((address_space(3))) unsigned int*)l, 16, 0, 0);
}

#define BARRIER() do { asm volatile("" ::: "memory"); \
    __builtin_amdgcn_s_barrier(); \
    asm volatile("" ::: "memory"); } while (0)
#define LGK0() asm volatile("s_waitcnt lgkmcnt(0)" ::: "memory")
#define VM(N)  asm volatile("s_waitcnt vmcnt(" #N ")" ::: "memory")

__global__ __launch_bounds__(512, 1)
void grouped_gemm_8ph(const unsigned short* __restrict__ xb,
                      const unsigned short* __restrict__ wb,
                      const float* __restrict__ bias,
                      const int* __restrict__ tpe,
                      float* __restrict__ out)
{
    // [parity buf][M- or N-half][128 rows * 64 K elems], linear (swizzle via
    // pre-swizzled global source + swizzled ds_read address).
    __shared__ __align__(16) unsigned short As[2][2][8192];
    __shared__ __align__(16) unsigned short Bs[2][2][8192];

    const int e = blockIdx.z;
    int off = 0, cnt = 0;
#pragma unroll
    for (int i = 0; i < 8; ++i) { int c = tpe[i]; if (i < e) off += c; if (i == e) cnt = c; }
    const int m0 = blockIdx.y * 256;
    if (m0 >= cnt) return;               // uniform exit
    const int rows = min(256, cnt - m0);
    const int row0 = off + m0;
    const int n0 = blockIdx.x * 256;

    const int t    = threadIdx.x;        // 0..511
    const int w    = t >> 6;             // wave 0..7
    const int lane = t & 63;
    const int wr   = w >> 2;             // M half (0..1) -> rows wr*128..+127
    const int wc   = w & 3;              // N quarter (0..3) -> cols wc*64..+63
    const int hb   = wc >> 1;            // B LDS half this wave reads
    const int fr   = lane & 15;
    const int fq   = lane >> 4;          // 0..3
    const int w512 = w * 512;            // uniform LDS elem offset per wave

    // ---- staging addresses (pre-swizzled global source; linear LDS dest) ----
    const int srow  = t >> 3;                                   // 0..63
    const int scswb = ((t & 7) * 16) ^ ((srow & 7) << 4);       // swizzled byte col
    const int scsw  = scswb >> 1;                               // elems

    // A row clamp handles ragged M (inactive rows re-read last valid row).
    const int ar00 = min(srow,       rows - 1);
    const int ar01 = min(srow + 64,  rows - 1);
    const int ar10 = min(srow + 128, rows - 1);
    const int ar11 = min(srow + 192, rows - 1);
    const unsigned short* aP00 = xb + (size_t)(row0 + ar00) * 2048 + scsw;
    const unsigned short* aP01 = xb + (size_t)(row0 + ar01) * 2048 + scsw;
    const unsigned short* aP10 = xb + (size_t)(row0 + ar10) * 2048 + scsw;
    const unsigned short* aP11 = xb + (size_t)(row0 + ar11) * 2048 + scsw;
    const unsigned short* wbe  = wb + (size_t)e * 4194304;
    const unsigned short* bP00 = wbe + (size_t)(n0 + srow      ) * 2048 + scsw;
    const unsigned short* bP01 = wbe + (size_t)(n0 + srow +  64) * 2048 + scsw;
    const unsigned short* bP10 = wbe + (size_t)(n0 + srow + 128) * 2048 + scsw;
    const unsigned short* bP11 = wbe + (size_t)(n0 + srow + 192) * 2048 + scsw;

#define ST_A0(P, K) do { gload16(aP00 + (K), &As[P][0][w512]); gload16(aP01 + (K), &As[P][0][4096 + w512]); } while (0)
#define ST_A1(P, K) do { gload16(aP10 + (K), &As[P][1][w512]); gload16(aP11 + (K), &As[P][1][4096 + w512]); } while (0)
#define ST_B0(P, K) do { gload16(bP00 + (K), &Bs[P][0][w512]); gload16(bP01 + (K), &Bs[P][0][4096 + w512]); } while (0)
#define ST_B1(P, K) do { gload16(bP10 + (K), &Bs[P][1][w512]); gload16(bP11 + (K), &Bs[P][1][4096 + w512]); } while (0)

    // ---- fragment-read swizzled column offsets (elems), ks = 0,1 ----
    const int cs0e = (((fq * 16)     ) ^ ((fr & 7) << 4)) >> 1;
    const int cs1e = (((fq * 16) + 64) ^ ((fr & 7) << 4)) >> 1;

    short8 af[4][2], bf[4][2];

#define RD_A(P, QR) do { _Pragma("unroll") for (int mi = 0; mi < 4; ++mi) { \
        const unsigned short* _ap = &As[P][wr][((QR) * 64 + mi * 16 + fr) * 64]; \
        af[mi][0] = *(const short8*)(_ap + cs0e); \
        af[mi][1] = *(const short8*)(_ap + cs1e); } } while (0)

#define RD_B(P, H2) do { _Pragma("unroll") for (int q = 0; q < 2; ++q) { \
        const unsigned short* _bp = &Bs[P][hb][((wc & 1) * 64 + ((H2) * 2 + q) * 16 + fr) * 64]; \
        bf[(H2) * 2 + q][0] = *(const short8*)(_bp + cs0e); \
        bf[(H2) * 2 + q][1] = *(const short8*)(_bp + cs1e); } } while (0)

    f32x4 acc[8][4] = {};

#define MM16(QR, QC) do { __builtin_amdgcn_s_setprio(1); \
        _Pragma("unroll") for (int ks = 0; ks < 2; ++ks) \
        _Pragma("unroll") for (int mi = 0; mi < 4; ++mi) \
        _Pragma("unroll") for (int q = 0; q < 2; ++q) \
            acc[(QR) * 4 + mi][(QC) * 2 + q] = __builtin_amdgcn_mfma_f32_16x16x32_bf16( \
                af[mi][ks], bf[(QC) * 2 + q][ks], acc[(QR) * 4 + mi][(QC) * 2 + q], 0, 0, 0); \
        __builtin_amdgcn_s_setprio(0); } while (0)

    // ---- prologue: tile0 -> buf0 (8 loads), tile1 partial -> buf1 (6 loads)
    ST_B0(0, 0); ST_B1(0, 0); ST_A0(0, 0); ST_A1(0, 0);
    ST_B0(1, 64); ST_B1(1, 64); ST_A0(1, 64);
    VM(6);                                // tile0 landed; 6 tile-1 loads in flight
    BARRIER();

    // ---- main loop: iteration i computes K-tiles 2i (buf0) and 2i+1 (buf1)
#pragma unroll 1
    for (int i = 0; i < 16; ++i) {
        const int kb = i * 128;           // elem K-offset of tile 2i
        const bool stg = (i < 15);
        // P1: quadrant (qr0,qc0) of tile 2i; stage A[buf1]h1 for tile 2i+1
        RD_A(0, 0); RD_B(0, 0);
        ST_A1(1, kb + 64);
        BARRIER(); LGK0();
        MM16(0, 0);
        BARRIER();
        // P2: (qr0,qc1)
        RD_B(0, 1);
        BARRIER(); LGK0();
        MM16(0, 1);
        BARRIER();
        // P3: (qr1,qc1); stage B[buf0] both halves for tile 2i+2
        RD_A(0, 1);
        if (stg) { ST_B0(0, kb + 128); ST_B1(0, kb + 128); }
        BARRIER(); LGK0();
        MM16(1, 1);
        BARRIER();
        // P4: (qr1,qc0); stage A[buf0]h0; vmcnt -> tile 2i+1 complete
        if (stg) ST_A0(0, kb + 128);
        BARRIER(); LGK0();
        MM16(1, 0);
        if (stg) { VM(6); } else { VM(0); }
        BARRIER();
        // P5: (qr0,qc0) of tile 2i+1; stage A[buf0]h1
        RD_A(1, 0); RD_B(1, 0);
        if (stg) ST_A1(0, kb + 128);
        BARRIER(); LGK0();
        MM16(0, 0);
        BARRIER();
        // P6: (qr0,qc1)
        RD_B(1, 1);
        BARRIER(); LGK0();
        MM16(0, 1);
        BARRIER();
        // P7: (qr1,qc1); stage B[buf1] both halves for tile 2i+3
        RD_A(1, 1);
        if (stg) { ST_B0(1, kb + 192); ST_B1(1, kb + 192); }
        BARRIER(); LGK0();
        MM16(1, 1);
        BARRIER();
        // P8: (qr1,qc0); stage A[buf1]h0; vmcnt -> tile 2i+2 complete
        if (stg) ST_A0(1, kb + 192);
        BARRIER(); LGK0();
        MM16(1, 0);
        if (stg) VM(6);
        BARRIER();
    }

    // ---- epilogue: row = wr*128 + mi*16 + fq*4 + r, col = n0 + wc*64 + nj*16 + fr
#pragma unroll
    for (int nj = 0; nj < 4; ++nj) {
        const int col = n0 + wc * 64 + nj * 16 + fr;
        const float bv = bias[e * 2048 + col];
#pragma unroll
        for (int mi = 0; mi < 8; ++mi) {
            const int rb = wr * 128 + mi * 16 + fq * 4;
#pragma unroll
            for (int r = 0; r < 4; ++r) {
                const int lr = rb + r;
                if (lr < rows)
                    out[(size_t)(row0 + lr) * 2048 + col] = acc[mi][nj][r] + bv;
            }
        }
    }
#undef ST_A0
#undef ST_A1
#undef ST_B0
#undef ST_B1
#undef RD_A
#undef RD_B
#undef MM16
}

// ---------------------------------------------------------------------------
// Fallback (verified fused kernel) for ws_size < 134 MB.
// ---------------------------------------------------------------------------
#define LDT 72

__global__ __launch_bounds__(256, 2)
void grouped_gemm_f32(const float* __restrict__ x,
                      const float* __restrict__ w,
                      const float* __restrict__ bias,
                      const int* __restrict__ tpe,
                      float* __restrict__ out)
{
    __shared__ __align__(16) unsigned short As[128 * LDT];
    __shared__ __align__(16) unsigned short Bs[128 * LDT];

    const int e = blockIdx.z;
    int off = 0, cnt = 0;
#pragma unroll
    for (int i = 0; i < 8; ++i) {
        int c = tpe[i];
        if (i < e) off += c;
        if (i == e) cnt = c;
    }
    const int m0 = blockIdx.y * 128;
    if (m0 >= cnt) return;
    const int rows = min(128, cnt - m0);
    const int row0 = off + m0;
    const int n0 = blockIdx.x * 128;

    const int tid = threadIdx.x;
    const int sr = tid >> 4;
    const int sc = (tid & 15) * 4;

    const float* gA = x + (size_t)row0 * 2048 + sc;
    const float* gB = w + (size_t)e * 4194304 + (size_t)(n0 + sr) * 2048 + sc;

    int arow[8];
#pragma unroll
    for (int p = 0; p < 8; ++p) {
        int r = sr + p * 16;
        arow[p] = ((r < rows) ? r : (rows - 1)) * 2048;
    }

    const int lane = tid & 63;
    const int wid  = tid >> 6;
    const int wm   = (wid & 1) * 64;
    const int wn   = (wid >> 1) * 64;
    const int fr   = lane & 15;
    const int fq   = lane >> 4;

    f32x4 acc[4][4];
#pragma unroll
    for (int i = 0; i < 4; ++i)
#pragma unroll
        for (int j = 0; j < 4; ++j)
            acc[i][j] = (f32x4){0.f, 0.f, 0.f, 0.f};

    for (int kt = 0; kt < 32; ++kt) {
        const int kk = kt * 64;
        __syncthreads();
#pragma unroll
        for (int p = 0; p < 8; ++p) {
            f32x4 a = *(const f32x4*)(gA + arow[p] + kk);
            f32x4 b = *(const f32x4*)(gB + p * 32768 + kk);
            const int rbase = (sr + p * 16) * LDT + sc;
            As[rbase + 0] = f2bf(a.x);
            As[rbase + 1] = f2bf(a.y);
            As[rbase + 2] = f2bf(a.z);
            As[rbase + 3] = f2bf(a.w);
            Bs[rbase + 0] = f2bf(b.x);
            Bs[rbase + 1] = f2bf(b.y);
            Bs[rbase + 2] = f2bf(b.z);
            Bs[rbase + 3] = f2bf(b.w);
        }
        __syncthreads();

#pragma unroll
        for (int ks = 0; ks < 2; ++ks) {
            short8 af[4], bfr[4];
#pragma unroll
            for (int i = 0; i < 4; ++i)
                af[i] = *(const short8*)(As + (wm + i * 16 + fr) * LDT + ks * 32 + fq * 8);
#pragma unroll
            for (int j = 0; j < 4; ++j)
                bfr[j] = *(const short8*)(Bs + (wn + j * 16 + fr) * LDT + ks * 32 + fq * 8);
#pragma unroll
            for (int i = 0; i < 4; ++i)
#pragma unroll
                for (int j = 0; j < 4; ++j)
                    acc[i][j] = __builtin_amdgcn_mfma_f32_16x16x32_bf16(af[i], bfr[j], acc[i][j], 0, 0, 0);
        }
    }

#pragma unroll
    for (int j = 0; j < 4; ++j) {
        const int col = n0 + wn + j * 16 + fr;
        const float bv = bias[e * 2048 + col];
#pragma unroll
        for (int i = 0; i < 4; ++i) {
            const int rbase = wm + i * 16 + fq * 4;
#pragma unroll
            for (int r = 0; r < 4; ++r) {
                const int lr = rbase + r;
                if (lr < rows)
                    out[(size_t)(row0 + lr) * 2048 + col] = acc[i][j][r] + bv;
            }
        }
    }
}

extern "C" void kernel_launch(void* const* d_in, const int* in_sizes, int n_in,
                              void* d_out, int out_size, void* d_ws, size_t ws_size,
                              hipStream_t stream) {
    const float* x    = (const float*)d_in[0];
    const float* w    = (const float*)d_in[1];
    const float* bias = (const float*)d_in[2];
    const int*   tpe  = (const int*)d_in[3];
    float* out = (float*)d_out;

    const size_t XE = (size_t)16384 * 2048;
    const size_t WE = (size_t)8 * 2048 * 2048;
    const size_t need = (XE + WE) * sizeof(unsigned short);  // 134,217,728 B

    if (ws_size >= need && d_ws != nullptr) {
        unsigned short* xb = (unsigned short*)d_ws;
        unsigned short* wbuf = xb + XE;
        cvt_f32_bf16<<<2048, 256, 0, stream>>>(x, xb, (int)(XE / 8));
        cvt_f32_bf16<<<2048, 256, 0, stream>>>(w, wbuf, (int)(WE / 8));
        // grid: n-tiles (2048/256=8), m-tiles (cap 2304/256=9), experts (8)
        dim3 grid(8, 9, 8);
        grouped_gemm_8ph<<<grid, 512, 0, stream>>>(xb, wbuf, bias, tpe, out);
    } else {
        dim3 grid(16, 18, 8);
        grouped_gemm_f32<<<grid, 256, 0, stream>>>(x, w, bias, tpe, out);
    }
}